// Round 15
// baseline (192.740 us; speedup 1.0000x reference)
//
#include <hip/hip_runtime.h>
#include <math.h>

// HoloAttentionV2 on MI355X (gfx950). Champion config (r10/r14) +
// grid-stride conversion kernel (G11) + vmcnt(2) staging-race fix.
// fp16 MFMA GEMMs, r8 4-phase schedule. Merged [10Wk|Wv] GEMM M-split into
// two 256-block launches; out GEMM grid (4,64). fp16 mod-2pi phase.
// 3-pass chunked complex scan.
// Shapes: B=2, T=8192, H=16, D=64, HD=DM=1024.

#define B_SZ 2
#define T_LEN 8192
#define H_N 16
#define D_N 64
#define HD 1024
#define DM 1024

#define NCH 128                 // chunks per chain
#define CH (T_LEN / NCH)        // 64 steps per chunk

typedef unsigned short u16;
typedef __attribute__((ext_vector_type(4))) unsigned short u16x4;
typedef __attribute__((ext_vector_type(8))) short s16x8;     // 16B LDS payload
typedef __attribute__((ext_vector_type(8))) _Float16 f16x8;  // MFMA operand
typedef __attribute__((ext_vector_type(4))) float f32x4;

__device__ __forceinline__ u16 f2h(float f) {
    return __builtin_bit_cast(u16, (_Float16)f);    // v_cvt_f16_f32, RNE
}
__device__ __forceinline__ float h2f(u16 h) {
    return (float)__builtin_bit_cast(_Float16, h);
}

// ---------------- single conversion kernel (grid-stride, 2048 blocks) -------
// slots [0, 4M): x -> xh. slots [4M, 4.75M): weights -> Wkv, Wob.
__global__ __launch_bounds__(256) void conv_all(
    const float* __restrict__ x, const float* __restrict__ Wk,
    const float* __restrict__ Wv, const float* __restrict__ Wo,
    u16* __restrict__ xh, u16* __restrict__ Wkv, u16* __restrict__ Wob)
{
    const size_t NX = 16384ull * 1024;                  // x elems
    const size_t total = (NX + 3ull * 1024 * 1024) / 4; // float4 slots
    const size_t stride = (size_t)gridDim.x * 256;
    for (size_t s = (size_t)blockIdx.x * 256 + threadIdx.x; s < total; s += stride) {
        size_t i = s * 4;
        if (i < NX) {
            float4 v = *reinterpret_cast<const float4*>(&x[i]);
            u16x4 o = { f2h(v.x), f2h(v.y), f2h(v.z), f2h(v.w) };
            *reinterpret_cast<u16x4*>(&xh[i]) = o;
        } else {
            size_t j = i - NX;                 // [0, 3M)
            int r = (int)(j >> 10);
            size_t src = j & (1024ull * 1024 - 1);
            float4 v;
            float sc = 1.f;
            u16* dst;
            size_t doff;
            if (r < 1024)      { v = *reinterpret_cast<const float4*>(&Wk[src]); sc = 10.f; dst = Wkv; doff = j; }
            else if (r < 2048) { v = *reinterpret_cast<const float4*>(&Wv[src]); dst = Wkv; doff = j; }
            else               { v = *reinterpret_cast<const float4*>(&Wo[src]); dst = Wob; doff = src; }
            u16x4 o = { f2h(sc * v.x), f2h(sc * v.y), f2h(sc * v.z), f2h(sc * v.w) };
            *reinterpret_cast<u16x4*>(&dst[doff]) = o;
        }
    }
}

// ---------------- 256x256 4-phase fp16 MFMA GEMM (r8 schedule) ----------------
// C[m,n] = sum_k A[m,k] * W[n,k]. 512 threads = 8 waves (2M x 4N),
// per-wave 128x64 output = 8x4 frags of 16x16. BK=64, double-buffered LDS
// (128 KiB): buf b at b*65536: A[256][64] then B[256][64], fp16,
// XOR-swizzled: byte_in_row ^= (row&7)<<4.
#define GBK 64

#define BAR()     asm volatile("s_barrier" ::: "memory")
#define VMCNT2()  asm volatile("s_waitcnt vmcnt(2)" ::: "memory")
#define VMCNT0()  asm volatile("s_waitcnt vmcnt(0)" ::: "memory")
#define LGKM8PRE() asm volatile("s_waitcnt lgkmcnt(8)" ::: "memory")
#define LGKM0_SB() do { asm volatile("s_waitcnt lgkmcnt(0)" ::: "memory"); \
                        __builtin_amdgcn_sched_barrier(0); } while (0)

template <int IMM>
__device__ __forceinline__ s16x8 dsr(unsigned base) {
    s16x8 r;
    asm volatile("ds_read_b128 %0, %1 offset:%2"
                 : "=v"(r) : "v"(base), "n"(IMM));
    return r;
}

__device__ __forceinline__ unsigned lds_addr(const void* p) {
    return (unsigned)(uintptr_t)(const __attribute__((address_space(3))) void*)p;
}

// 16 fp16 MFMA (caller wraps clusters with setprio)
#define MFMA_Q(mh, nh)                                               \
  {                                                                  \
    _Pragma("unroll")                                                \
    for (int ks_ = 0; ks_ < 2; ++ks_)                                \
      _Pragma("unroll")                                              \
      for (int m_ = 0; m_ < 4; ++m_)                                 \
        _Pragma("unroll")                                            \
        for (int n_ = 0; n_ < 2; ++n_)                               \
          acc[(mh)*4 + m_][(nh)*2 + n_] =                            \
            __builtin_amdgcn_mfma_f32_16x16x32_f16(                  \
              __builtin_bit_cast(f16x8, aR[m_][ks_]),                \
              __builtin_bit_cast(f16x8, bR[(nh)*2 + n_][ks_]),       \
              acc[(mh)*4 + m_][(nh)*2 + n_], 0, 0, 0);               \
  }

// A rows (8 of wave tile, offset ofs = 0 for rows 0-63, 8192 for rows 64-127)
#define RD_A(ph, ofs)                                                          \
  aR[0][0]=dsr<(ofs)+0>(bA[ph][0]);    aR[1][0]=dsr<(ofs)+2048>(bA[ph][0]);    \
  aR[2][0]=dsr<(ofs)+4096>(bA[ph][0]); aR[3][0]=dsr<(ofs)+6144>(bA[ph][0]);    \
  aR[0][1]=dsr<(ofs)+0>(bA[ph][1]);    aR[1][1]=dsr<(ofs)+2048>(bA[ph][1]);    \
  aR[2][1]=dsr<(ofs)+4096>(bA[ph][1]); aR[3][1]=dsr<(ofs)+6144>(bA[ph][1]);
#define RD_B01(ph)                                                             \
  bR[0][0]=dsr<0>(bB[ph][0]);    bR[1][0]=dsr<2048>(bB[ph][0]);                \
  bR[0][1]=dsr<0>(bB[ph][1]);    bR[1][1]=dsr<2048>(bB[ph][1]);
#define RD_B23(ph)                                                             \
  bR[2][0]=dsr<4096>(bB[ph][0]); bR[3][0]=dsr<6144>(bB[ph][0]);                \
  bR[2][1]=dsr<4096>(bB[ph][1]); bR[3][1]=dsr<6144>(bB[ph][1]);

// One K-tile, 2 phases. ph = buffer.
// vmcnt(2) (was 4): at each P2 wait, the in-flight FIFO is
// [A(next)x2, B(next+1)x2]; leaving only the 2 newest B's guarantees the
// A half-tiles the NEXT phase-group ds_reads have landed (the old vmcnt(4)
// formally raced those reads; loads landed in practice, but vmcnt(2) makes
// it architectural at ~0 cost since A was issued a full phase earlier).
#define PHASE_GROUP(ph)                                              \
  {                                                                  \
    RD_A(ph, 0); RD_B01(ph); RD_B23(ph);                             \
    LGKM8PRE();                                                      \
    if ((ph) == 0)    { STAGE_A(2*t+1, 1, 0); STAGE_A(2*t+1, 1, 1); }\
    else if (gm)      { STAGE_A(2*t+2, 0, 0); STAGE_A(2*t+2, 0, 1); }\
    BAR(); LGKM0_SB();                                               \
    __builtin_amdgcn_s_setprio(1);                                   \
    MFMA_Q(0, 0); MFMA_Q(0, 1);                                      \
    __builtin_amdgcn_s_setprio(0);                                   \
    BAR();                                                           \
    RD_A(ph, 8192);                                                  \
    if (gm) { STAGE_B(2*t+2+(ph), (ph), 0);                          \
              STAGE_B(2*t+2+(ph), (ph), 1); VMCNT2(); }              \
    else    { VMCNT0(); }                                            \
    BAR(); LGKM0_SB();                                               \
    __builtin_amdgcn_s_setprio(1);                                   \
    MFMA_Q(1, 0); MFMA_Q(1, 1);                                      \
    __builtin_amdgcn_s_setprio(0);                                   \
    BAR();                                                           \
  }

// Stage one half-tile (128 rows x 64 cols fp16 = 16 KB) via global_load_lds.
// LDS dest linear; global src pre-inverse-swizzled (rule #21).
__device__ __forceinline__ void stage_half(
    const u16* __restrict__ g, int ld, int rowbase, int kbase,
    char* ldshalf, int wid, int lane)
{
#pragma unroll
    for (int s = 0; s < 2; ++s) {
        const int slot = s * 512 + wid * 64 + lane;
        const int r = slot >> 3;
        const int cb = ((slot & 7) << 4) ^ ((r & 7) << 4);
        const u16* gp = g + (size_t)(rowbase + r) * ld + kbase + (cb >> 1);
        __builtin_amdgcn_global_load_lds(
            (const __attribute__((address_space(1))) void*)gp,
            (__attribute__((address_space(3))) void*)(ldshalf + s * 8192 + wid * 1024),
            16, 0, 0);
    }
}

// mode 0: f32 store to Cv (ldc). mode 3: n0<1024 -> fp16 mod-2pi phase to Cv
// (ld 1024); n0>=1024 -> fp16 v to Vv (ld 1024, col-1024).
// Swizzle: xcd = flat&7; per-XCD 1<<bshift m-tiles; bx-major order.
__global__ __launch_bounds__(512, 2) void gemm_mfma256(
    const u16* __restrict__ A, int lda, const u16* __restrict__ W, int ldw,
    void* __restrict__ Cv, int ldc, void* __restrict__ Vv, int K, int mode,
    int m_base, int bshift)
{
    __shared__ __align__(16) char lds[131072];

    const int tid  = threadIdx.x;
    const int lane = tid & 63;
    const int wid  = tid >> 6;      // 0..7
    const int wm   = wid >> 2;      // 0..1
    const int wn   = wid & 3;       // 0..3
    const int l15  = lane & 15;
    const int hib  = (lane >> 4) << 4;

    const int flat = blockIdx.y * gridDim.x + blockIdx.x;
    const int xcd  = flat & 7;
    const int c    = flat >> 3;
    const int byl  = c & ((1 << bshift) - 1);
    const int bx   = c >> bshift;
    const int m0   = ((xcd << bshift) + byl) * 256 + m_base;
    const int n0   = bx * 256;

    const int NK2 = K / (2 * GBK);

    f32x4 acc[8][4] = {};
    s16x8 aR[4][2], bR[4][2];

    const int Xl = (l15 & 7) << 4;
    unsigned bA[2][2], bB[2][2];
#pragma unroll
    for (int p2 = 0; p2 < 2; ++p2)
#pragma unroll
        for (int ks = 0; ks < 2; ++ks) {
            bA[p2][ks] = lds_addr(lds) + p2 * 65536 +
                         (wm * 128 + l15) * 128 + ((ks * 64 + hib) ^ Xl);
            bB[p2][ks] = lds_addr(lds) + p2 * 65536 + 32768 +
                         (wn * 64 + l15) * 128 + ((ks * 64 + hib) ^ Xl);
        }

    auto STAGE_A = [&](int kt, int buf, int h) {
        stage_half(A, lda, m0 + h * 128, kt * GBK,
                   (char*)lds + buf * 65536 + h * 16384, wid, lane);
    };
    auto STAGE_B = [&](int kt, int buf, int h) {
        stage_half(W, ldw, n0 + h * 128, kt * GBK,
                   (char*)lds + buf * 65536 + 32768 + h * 16384, wid, lane);
    };

    // prologue: ktile0 -> buf0 (B,A); ktile1 -> buf1 (B).
    // vmcnt(2): guarantee ktile0's B AND A landed (old vmcnt(4) left A0 in
    // flight when the first RD_A issued); B(1) pair stays in flight.
    STAGE_B(0, 0, 0); STAGE_B(0, 0, 1);
    STAGE_A(0, 0, 0); STAGE_A(0, 0, 1);
    STAGE_B(1, 1, 0); STAGE_B(1, 1, 1);
    VMCNT2();
    BAR();

    for (int t = 0; t < NK2; ++t) {
        const bool gm = (t < NK2 - 1);
        PHASE_GROUP(0)
        PHASE_GROUP(1)
    }

    // epilogue: C/D layout col=lane&15, row=(lane>>4)*4+r per 16x16 frag
    const float TWOPI  = 6.2831853071795864f;
    const float INV2PI = 0.15915494309189535f;
    float* Cf = (float*)Cv;
    u16*   Ph = (u16*)Cv;
    u16*   Vh = (u16*)Vv;
    const bool isPhase = (n0 < 1024);
#pragma unroll
    for (int m = 0; m < 8; ++m) {
#pragma unroll
        for (int n = 0; n < 4; ++n) {
            const int r0  = m0 + wm * 128 + m * 16 + ((lane >> 4) << 2);
            const int col = n0 + wn * 64 + n * 16 + l15;
#pragma unroll
            for (int r = 0; r < 4; ++r) {
                const float val = acc[m][n][r];
                if (mode == 0) {
                    Cf[(size_t)(r0 + r) * ldc + col] = val;
                } else if (isPhase) {
                    float red = fmaf(-TWOPI, rintf(val * INV2PI), val);
                    Ph[(size_t)(r0 + r) * 1024 + col] = f2h(red);
                } else {
                    Vh[(size_t)(r0 + r) * 1024 + (col - 1024)] = f2h(val);
                }
            }
        }
    }
}

// ---------------- scan ----------------
// phase is fp16, pre-reduced to [-pi,pi] by the GEMM epilogue.
__device__ __forceinline__ void rotor_sincos(int t, double fd, float* sr, float* cr)
{
    const double twopi = 6.283185307179586;
    const double inv2pi = 0.15915494309189535;
    double ang = (double)t * fd;
    double n = rint(ang * inv2pi);
    float red = (float)(ang - n * twopi);
    __sincosf(red, sr, cr);
}

__global__ __launch_bounds__(256) void scan_pass1(
    const u16* __restrict__ vArr, const u16* __restrict__ phase,
    float* __restrict__ cs)
{
    int gw = (blockIdx.x * 256 + threadIdx.x) >> 6;
    int d = threadIdx.x & 63;
    int c = gw & (NCH - 1);
    int h = (gw >> 7) & (H_N - 1);
    int b = gw >> 11;

    double fd = 6.283185307179586 * ((double)(h + 1) / 16.0)
              * pow(10000.0, -(double)d / 64.0);

    int t0 = c * CH;
    size_t base = ((size_t)b * T_LEN + t0) * HD + (size_t)h * D_N + d;

    float cr, sr;
    rotor_sincos(t0, fd, &sr, &cr);
    float cf, sf;
    sincosf((float)fd, &sf, &cf);

    float cp = 0.f, spv = 0.f;
    if (t0 > 0) {
        float thp = h2f(phase[base - HD]);
        __sincosf(thp, &spv, &cp);
    }

    float sp_re = 0.f, sp_im = 0.f, sa_re = 0.f, sa_im = 0.f;
    for (int i = 0; i < CH; ++i) {
        size_t idx = base + (size_t)i * HD;
        float v = h2f(vArr[idx]);
        float th = h2f(phase[idx]);
        sp_re = fmaf(v, cr, sp_re);
        sp_im = fmaf(v, sr, sp_im);
        sa_re = fmaf(v, cp, sa_re);
        sa_im = fmaf(-v, spv, sa_im);
        __sincosf(th, &spv, &cp);
        float nc = fmaf(cr, cf, -sr * sf);
        float ns = fmaf(sr, cf,  cr * sf);
        cr = nc; sr = ns;
    }

    const size_t NT = (size_t)B_SZ * H_N * NCH * D_N;
    size_t ci = (size_t)gw * D_N + d;
    cs[ci] = sp_re;
    cs[NT + ci] = sp_im;
    cs[2 * NT + ci] = sa_re;
    cs[3 * NT + ci] = sa_im;
}

__global__ void scan_pass2(float* __restrict__ cs)
{
    int tid = blockIdx.x * blockDim.x + threadIdx.x;
    if (tid >= B_SZ * H_N * D_N) return;
    int d = tid & 63;
    int bh = tid >> 6;
    size_t base = (size_t)bh * NCH * D_N + d;
    const size_t NT = (size_t)B_SZ * H_N * NCH * D_N;
    float r0 = 0.f, r1 = 0.f, r2 = 0.f, r3 = 0.f;
    for (int c = 0; c < NCH; ++c) {
        size_t i = base + (size_t)c * D_N;
        float a = cs[i], b2 = cs[NT + i], c2 = cs[2 * NT + i], d2 = cs[3 * NT + i];
        cs[i] = r0; cs[NT + i] = r1; cs[2 * NT + i] = r2; cs[3 * NT + i] = r3;
        r0 += a; r1 += b2; r2 += c2; r3 += d2;
    }
}

__global__ __launch_bounds__(256) void scan_pass3(
    const u16* __restrict__ vArr, const u16* __restrict__ phase,
    const float* __restrict__ cs, const float* __restrict__ gate,
    u16* __restrict__ y)
{
    int gw = (blockIdx.x * 256 + threadIdx.x) >> 6;
    int d = threadIdx.x & 63;
    int c = gw & (NCH - 1);
    int h = (gw >> 7) & (H_N - 1);
    int b = gw >> 11;

    double fd = 6.283185307179586 * ((double)(h + 1) / 16.0)
              * pow(10000.0, -(double)d / 64.0);
    float g0 = gate[h * 2 + 0];
    float g1 = gate[h * 2 + 1];

    int t0 = c * CH;
    size_t base = ((size_t)b * T_LEN + t0) * HD + (size_t)h * D_N + d;

    const size_t NT = (size_t)B_SZ * H_N * NCH * D_N;
    size_t ci = (size_t)gw * D_N + d;
    float ap_re = cs[ci];
    float ap_im = cs[NT + ci];
    float aa_re = cs[2 * NT + ci];
    float aa_im = cs[3 * NT + ci];

    float cr, sr;
    rotor_sincos(t0, fd, &sr, &cr);
    float cf, sf;
    sincosf((float)fd, &sf, &cf);

    float cp = 0.f, spv = 0.f;
    if (t0 > 0) {
        float thp = h2f(phase[base - HD]);
        __sincosf(thp, &spv, &cp);
    }

    for (int i = 0; i < CH; ++i) {
        int t = t0 + i;
        size_t idx = base + (size_t)i * HD;
        float v = h2f(vArr[idx]);
        float th = h2f(phase[idx]);
        ap_re = fmaf(v, cr, ap_re);
        ap_im = fmaf(v, sr, ap_im);
        aa_re = fmaf(v, cp, aa_re);
        aa_im = fmaf(-v, spv, aa_im);
        float op = fmaf(ap_re, cr, ap_im * sr);
        float ck, sk;
        __sincosf(th, &sk, &ck);
        float oa = fmaf(aa_re, ck, -aa_im * sk);
        float sc = rsqrtf((float)(t + 1));
        y[idx] = f2h((g0 * op + g1 * oa) * sc);
        cp = ck; spv = sk;
        float nc = fmaf(cr, cf, -sr * sf);
        float ns = fmaf(sr, cf,  cr * sf);
        cr = nc; sr = ns;
    }
}

// ---------------- launch ----------------
extern "C" void kernel_launch(void* const* d_in, const int* in_sizes, int n_in,
                              void* d_out, int out_size, void* d_ws, size_t ws_size,
                              hipStream_t stream)
{
    const float* x    = (const float*)d_in[0];
    const float* Wk   = (const float*)d_in[1];
    const float* Wv   = (const float*)d_in[2];
    const float* Wo   = (const float*)d_in[3];
    const float* gate = (const float*)d_in[4];
    float* out = (float*)d_out;

    // ws layout (MiB offsets):
    //   0  : xh   [16384][1024] fp16 = 32   -- yb aliases it after merged GEMM
    //   32 : vb   [16384][1024] fp16 = 32
    //   64 : cs   4 * 2*16*128*64 f32 = 4
    //   68 : Wkv  [2048][1024] fp16  = 4    (10Wk | Wv)
    //   72 : Wob  [1024][1024] fp16  = 2
    //   74 : ph16 [16384][1024] fp16 = 32   (mod-2pi phase)   total 106 MiB
    char* wsb = (char*)d_ws;
    u16*   xh   = (u16*)wsb;
    u16*   yb   = (u16*)wsb;                      // alias: xh dead after merged GEMM
    u16*   vb   = (u16*)(wsb + (32ull << 20));
    float* cs   = (float*)(wsb + (64ull << 20));
    u16*   Wkv  = (u16*)(wsb + (68ull << 20));
    u16*   Wob  = (u16*)(wsb + (72ull << 20));
    u16*   ph16 = (u16*)(wsb + (74ull << 20));

    // all conversions: grid-stride, 2048 blocks (~9.5 float4/thread)
    hipLaunchKernelGGL(conv_all, dim3(2048), dim3(256), 0, stream,
                       x, Wk, Wv, Wo, xh, Wkv, Wob);

    const dim3 gblk(512);

    // [phase | v] = xh @ [10Wk | Wv]^T  (M=16384, N=2048, K=1024),
    // M-split into two 256-block launches (1 block/CU each).
    hipLaunchKernelGGL(gemm_mfma256, dim3(8, 32), gblk, 0, stream,
                       xh, 1024, Wkv, 1024, (void*)ph16, 1024, (void*)vb, 1024, 3,
                       0, 2);
    hipLaunchKernelGGL(gemm_mfma256, dim3(8, 32), gblk, 0, stream,
                       xh, 1024, Wkv, 1024, (void*)ph16, 1024, (void*)vb, 1024, 3,
                       8192, 2);

    const int waves = B_SZ * H_N * NCH;   // 4096
    hipLaunchKernelGGL(scan_pass1, dim3(waves / 4), dim3(256), 0, stream, vb, ph16, cs);
    hipLaunchKernelGGL(scan_pass2, dim3(8), dim3(256), 0, stream, cs);
    hipLaunchKernelGGL(scan_pass3, dim3(waves / 4), dim3(256), 0, stream, vb, ph16, cs, gate, yb);

    // out = yb @ Wo^T   (M=16384, N=1024, K=1024) -> d_out f32
    hipLaunchKernelGGL(gemm_mfma256, dim3(4, 64), gblk, 0, stream,
                       yb, 1024, Wob, 1024, (void*)out, HD, (void*)0, 1024, 0,
                       0, 3);
}

// Round 16
// 182.153 us; speedup vs baseline: 1.0581x; 1.0581x over previous
//
#include <hip/hip_runtime.h>
#include <math.h>

// HoloAttentionV2 on MI355X (gfx950). CHAMPION CONFIG (r14, restored verbatim).
// fp16 MFMA GEMMs, r8 4-phase schedule. Merged [10Wk|Wv] GEMM M-split into two
// 256-block launches (grid (8,32), xcd owns M-groups); out GEMM grid (4,64).
// fp16 mod-2pi phase. 3-pass chunked complex scan.
// Tested & rejected: 8-phase template (r4), asm-read scheduling (r5), barrier
// halving (r6), 1-barrier tile (r9), chaining (r11-r13), grid-stride conv +
// vmcnt(2) (r15). This is the measured optimum.
// Shapes: B=2, T=8192, H=16, D=64, HD=DM=1024.

#define B_SZ 2
#define T_LEN 8192
#define H_N 16
#define D_N 64
#define HD 1024
#define DM 1024

#define NCH 128                 // chunks per chain
#define CH (T_LEN / NCH)        // 64 steps per chunk

typedef unsigned short u16;
typedef __attribute__((ext_vector_type(4))) unsigned short u16x4;
typedef __attribute__((ext_vector_type(8))) short s16x8;     // 16B LDS payload
typedef __attribute__((ext_vector_type(8))) _Float16 f16x8;  // MFMA operand
typedef __attribute__((ext_vector_type(4))) float f32x4;

__device__ __forceinline__ u16 f2h(float f) {
    return __builtin_bit_cast(u16, (_Float16)f);    // v_cvt_f16_f32, RNE
}
__device__ __forceinline__ float h2f(u16 h) {
    return (float)__builtin_bit_cast(_Float16, h);
}

// ---------------- single conversion kernel ----------------
// blocks [0,16384): x -> xh. blocks [16384,19456): weights -> Wkv, Wob.
__global__ __launch_bounds__(256) void conv_all(
    const float* __restrict__ x, const float* __restrict__ Wk,
    const float* __restrict__ Wv, const float* __restrict__ Wo,
    u16* __restrict__ xh, u16* __restrict__ Wkv, u16* __restrict__ Wob)
{
    size_t i = ((size_t)blockIdx.x * 256 + threadIdx.x) * 4;
    const size_t NX = 16384ull * 1024;
    if (i < NX) {
        float4 v = *reinterpret_cast<const float4*>(&x[i]);
        u16x4 o = { f2h(v.x), f2h(v.y), f2h(v.z), f2h(v.w) };
        *reinterpret_cast<u16x4*>(&xh[i]) = o;
    } else {
        size_t j = i - NX;                 // [0, 3M)
        int r = (int)(j >> 10);
        size_t src = j & (1024ull * 1024 - 1);
        float4 v;
        float s = 1.f;
        u16* dst;
        size_t doff;
        if (r < 1024)      { v = *reinterpret_cast<const float4*>(&Wk[src]); s = 10.f; dst = Wkv; doff = j; }
        else if (r < 2048) { v = *reinterpret_cast<const float4*>(&Wv[src]); dst = Wkv; doff = j; }
        else               { v = *reinterpret_cast<const float4*>(&Wo[src]); dst = Wob; doff = src; }
        u16x4 o = { f2h(s * v.x), f2h(s * v.y), f2h(s * v.z), f2h(s * v.w) };
        *reinterpret_cast<u16x4*>(&dst[doff]) = o;
    }
}

// ---------------- 256x256 4-phase fp16 MFMA GEMM (r8 schedule) ----------------
// C[m,n] = sum_k A[m,k] * W[n,k]. 512 threads = 8 waves (2M x 4N),
// per-wave 128x64 output = 8x4 frags of 16x16. BK=64, double-buffered LDS
// (128 KiB): buf b at b*65536: A[256][64] then B[256][64], fp16,
// XOR-swizzled: byte_in_row ^= (row&7)<<4.
#define GBK 64

#define BAR()     asm volatile("s_barrier" ::: "memory")
#define VMCNT4()  asm volatile("s_waitcnt vmcnt(4)" ::: "memory")
#define VMCNT0()  asm volatile("s_waitcnt vmcnt(0)" ::: "memory")
#define LGKM8PRE() asm volatile("s_waitcnt lgkmcnt(8)" ::: "memory")
#define LGKM0_SB() do { asm volatile("s_waitcnt lgkmcnt(0)" ::: "memory"); \
                        __builtin_amdgcn_sched_barrier(0); } while (0)

template <int IMM>
__device__ __forceinline__ s16x8 dsr(unsigned base) {
    s16x8 r;
    asm volatile("ds_read_b128 %0, %1 offset:%2"
                 : "=v"(r) : "v"(base), "n"(IMM));
    return r;
}

__device__ __forceinline__ unsigned lds_addr(const void* p) {
    return (unsigned)(uintptr_t)(const __attribute__((address_space(3))) void*)p;
}

// 16 fp16 MFMA (caller wraps clusters with setprio)
#define MFMA_Q(mh, nh)                                               \
  {                                                                  \
    _Pragma("unroll")                                                \
    for (int ks_ = 0; ks_ < 2; ++ks_)                                \
      _Pragma("unroll")                                              \
      for (int m_ = 0; m_ < 4; ++m_)                                 \
        _Pragma("unroll")                                            \
        for (int n_ = 0; n_ < 2; ++n_)                               \
          acc[(mh)*4 + m_][(nh)*2 + n_] =                            \
            __builtin_amdgcn_mfma_f32_16x16x32_f16(                  \
              __builtin_bit_cast(f16x8, aR[m_][ks_]),                \
              __builtin_bit_cast(f16x8, bR[(nh)*2 + n_][ks_]),       \
              acc[(mh)*4 + m_][(nh)*2 + n_], 0, 0, 0);               \
  }

// A rows (8 of wave tile, offset ofs = 0 for rows 0-63, 8192 for rows 64-127)
#define RD_A(ph, ofs)                                                          \
  aR[0][0]=dsr<(ofs)+0>(bA[ph][0]);    aR[1][0]=dsr<(ofs)+2048>(bA[ph][0]);    \
  aR[2][0]=dsr<(ofs)+4096>(bA[ph][0]); aR[3][0]=dsr<(ofs)+6144>(bA[ph][0]);    \
  aR[0][1]=dsr<(ofs)+0>(bA[ph][1]);    aR[1][1]=dsr<(ofs)+2048>(bA[ph][1]);    \
  aR[2][1]=dsr<(ofs)+4096>(bA[ph][1]); aR[3][1]=dsr<(ofs)+6144>(bA[ph][1]);
#define RD_B01(ph)                                                             \
  bR[0][0]=dsr<0>(bB[ph][0]);    bR[1][0]=dsr<2048>(bB[ph][0]);                \
  bR[0][1]=dsr<0>(bB[ph][1]);    bR[1][1]=dsr<2048>(bB[ph][1]);
#define RD_B23(ph)                                                             \
  bR[2][0]=dsr<4096>(bB[ph][0]); bR[3][0]=dsr<6144>(bB[ph][0]);                \
  bR[2][1]=dsr<4096>(bB[ph][1]); bR[3][1]=dsr<6144>(bB[ph][1]);

// One K-tile, 2 phases. ph = buffer. Race audit: B-stage (P2 -> buf[ph].B)
// after P1's lgkm0 drained this group's B reads; A-stage (P1 -> buf[ph^1].A)
// after prev group's P2 lgkm0 drained its A-bottom reads. vmcnt(4) at P2
// drains next buffer's A+B exactly, keeps following B half-pair in flight.
// (A-half formal in-flight window is covered by >1200 cy of MFMA+barriers
// between stage-issue and first read; vmcnt(2) "fix" measured -10 us, r15.)
#define PHASE_GROUP(ph)                                              \
  {                                                                  \
    RD_A(ph, 0); RD_B01(ph); RD_B23(ph);                             \
    LGKM8PRE();                                                      \
    if ((ph) == 0)    { STAGE_A(2*t+1, 1, 0); STAGE_A(2*t+1, 1, 1); }\
    else if (gm)      { STAGE_A(2*t+2, 0, 0); STAGE_A(2*t+2, 0, 1); }\
    BAR(); LGKM0_SB();                                               \
    __builtin_amdgcn_s_setprio(1);                                   \
    MFMA_Q(0, 0); MFMA_Q(0, 1);                                      \
    __builtin_amdgcn_s_setprio(0);                                   \
    BAR();                                                           \
    RD_A(ph, 8192);                                                  \
    if (gm) { STAGE_B(2*t+2+(ph), (ph), 0);                          \
              STAGE_B(2*t+2+(ph), (ph), 1); VMCNT4(); }              \
    else    { VMCNT0(); }                                            \
    BAR(); LGKM0_SB();                                               \
    __builtin_amdgcn_s_setprio(1);                                   \
    MFMA_Q(1, 0); MFMA_Q(1, 1);                                      \
    __builtin_amdgcn_s_setprio(0);                                   \
    BAR();                                                           \
  }

// Stage one half-tile (128 rows x 64 cols fp16 = 16 KB) via global_load_lds.
// LDS dest linear; global src pre-inverse-swizzled (rule #21).
__device__ __forceinline__ void stage_half(
    const u16* __restrict__ g, int ld, int rowbase, int kbase,
    char* ldshalf, int wid, int lane)
{
#pragma unroll
    for (int s = 0; s < 2; ++s) {
        const int slot = s * 512 + wid * 64 + lane;
        const int r = slot >> 3;
        const int cb = ((slot & 7) << 4) ^ ((r & 7) << 4);
        const u16* gp = g + (size_t)(rowbase + r) * ld + kbase + (cb >> 1);
        __builtin_amdgcn_global_load_lds(
            (const __attribute__((address_space(1))) void*)gp,
            (__attribute__((address_space(3))) void*)(ldshalf + s * 8192 + wid * 1024),
            16, 0, 0);
    }
}

// mode 0: f32 store to Cv (ldc). mode 3: n0<1024 -> fp16 mod-2pi phase to Cv
// (ld 1024); n0>=1024 -> fp16 v to Vv (ld 1024, col-1024).
// Swizzle: xcd = flat&7; per-XCD 1<<bshift m-tiles; bx-major order.
__global__ __launch_bounds__(512, 2) void gemm_mfma256(
    const u16* __restrict__ A, int lda, const u16* __restrict__ W, int ldw,
    void* __restrict__ Cv, int ldc, void* __restrict__ Vv, int K, int mode,
    int m_base, int bshift)
{
    __shared__ __align__(16) char lds[131072];

    const int tid  = threadIdx.x;
    const int lane = tid & 63;
    const int wid  = tid >> 6;      // 0..7
    const int wm   = wid >> 2;      // 0..1
    const int wn   = wid & 3;       // 0..3
    const int l15  = lane & 15;
    const int hib  = (lane >> 4) << 4;

    const int flat = blockIdx.y * gridDim.x + blockIdx.x;
    const int xcd  = flat & 7;
    const int c    = flat >> 3;
    const int byl  = c & ((1 << bshift) - 1);
    const int bx   = c >> bshift;
    const int m0   = ((xcd << bshift) + byl) * 256 + m_base;
    const int n0   = bx * 256;

    const int NK2 = K / (2 * GBK);

    f32x4 acc[8][4] = {};
    s16x8 aR[4][2], bR[4][2];

    const int Xl = (l15 & 7) << 4;
    unsigned bA[2][2], bB[2][2];
#pragma unroll
    for (int p2 = 0; p2 < 2; ++p2)
#pragma unroll
        for (int ks = 0; ks < 2; ++ks) {
            bA[p2][ks] = lds_addr(lds) + p2 * 65536 +
                         (wm * 128 + l15) * 128 + ((ks * 64 + hib) ^ Xl);
            bB[p2][ks] = lds_addr(lds) + p2 * 65536 + 32768 +
                         (wn * 64 + l15) * 128 + ((ks * 64 + hib) ^ Xl);
        }

    auto STAGE_A = [&](int kt, int buf, int h) {
        stage_half(A, lda, m0 + h * 128, kt * GBK,
                   (char*)lds + buf * 65536 + h * 16384, wid, lane);
    };
    auto STAGE_B = [&](int kt, int buf, int h) {
        stage_half(W, ldw, n0 + h * 128, kt * GBK,
                   (char*)lds + buf * 65536 + 32768 + h * 16384, wid, lane);
    };

    // prologue: ktile0 -> buf0 (B,A); ktile1 -> buf1 (B)
    STAGE_B(0, 0, 0); STAGE_B(0, 0, 1);
    STAGE_A(0, 0, 0); STAGE_A(0, 0, 1);
    STAGE_B(1, 1, 0); STAGE_B(1, 1, 1);
    VMCNT4();
    BAR();

    for (int t = 0; t < NK2; ++t) {
        const bool gm = (t < NK2 - 1);
        PHASE_GROUP(0)
        PHASE_GROUP(1)
    }

    // epilogue: C/D layout col=lane&15, row=(lane>>4)*4+r per 16x16 frag
    const float TWOPI  = 6.2831853071795864f;
    const float INV2PI = 0.15915494309189535f;
    float* Cf = (float*)Cv;
    u16*   Ph = (u16*)Cv;
    u16*   Vh = (u16*)Vv;
    const bool isPhase = (n0 < 1024);
#pragma unroll
    for (int m = 0; m < 8; ++m) {
#pragma unroll
        for (int n = 0; n < 4; ++n) {
            const int r0  = m0 + wm * 128 + m * 16 + ((lane >> 4) << 2);
            const int col = n0 + wn * 64 + n * 16 + l15;
#pragma unroll
            for (int r = 0; r < 4; ++r) {
                const float val = acc[m][n][r];
                if (mode == 0) {
                    Cf[(size_t)(r0 + r) * ldc + col] = val;
                } else if (isPhase) {
                    float red = fmaf(-TWOPI, rintf(val * INV2PI), val);
                    Ph[(size_t)(r0 + r) * 1024 + col] = f2h(red);
                } else {
                    Vh[(size_t)(r0 + r) * 1024 + (col - 1024)] = f2h(val);
                }
            }
        }
    }
}

// ---------------- scan ----------------
// phase is fp16, pre-reduced to [-pi,pi] by the GEMM epilogue.
__device__ __forceinline__ void rotor_sincos(int t, double fd, float* sr, float* cr)
{
    const double twopi = 6.283185307179586;
    const double inv2pi = 0.15915494309189535;
    double ang = (double)t * fd;
    double n = rint(ang * inv2pi);
    float red = (float)(ang - n * twopi);
    __sincosf(red, sr, cr);
}

__global__ __launch_bounds__(256) void scan_pass1(
    const u16* __restrict__ vArr, const u16* __restrict__ phase,
    float* __restrict__ cs)
{
    int gw = (blockIdx.x * 256 + threadIdx.x) >> 6;
    int d = threadIdx.x & 63;
    int c = gw & (NCH - 1);
    int h = (gw >> 7) & (H_N - 1);
    int b = gw >> 11;

    double fd = 6.283185307179586 * ((double)(h + 1) / 16.0)
              * pow(10000.0, -(double)d / 64.0);

    int t0 = c * CH;
    size_t base = ((size_t)b * T_LEN + t0) * HD + (size_t)h * D_N + d;

    float cr, sr;
    rotor_sincos(t0, fd, &sr, &cr);
    float cf, sf;
    sincosf((float)fd, &sf, &cf);

    float cp = 0.f, spv = 0.f;
    if (t0 > 0) {
        float thp = h2f(phase[base - HD]);
        __sincosf(thp, &spv, &cp);
    }

    float sp_re = 0.f, sp_im = 0.f, sa_re = 0.f, sa_im = 0.f;
    for (int i = 0; i < CH; ++i) {
        size_t idx = base + (size_t)i * HD;
        float v = h2f(vArr[idx]);
        float th = h2f(phase[idx]);
        sp_re = fmaf(v, cr, sp_re);
        sp_im = fmaf(v, sr, sp_im);
        sa_re = fmaf(v, cp, sa_re);
        sa_im = fmaf(-v, spv, sa_im);
        __sincosf(th, &spv, &cp);
        float nc = fmaf(cr, cf, -sr * sf);
        float ns = fmaf(sr, cf,  cr * sf);
        cr = nc; sr = ns;
    }

    const size_t NT = (size_t)B_SZ * H_N * NCH * D_N;
    size_t ci = (size_t)gw * D_N + d;
    cs[ci] = sp_re;
    cs[NT + ci] = sp_im;
    cs[2 * NT + ci] = sa_re;
    cs[3 * NT + ci] = sa_im;
}

__global__ void scan_pass2(float* __restrict__ cs)
{
    int tid = blockIdx.x * blockDim.x + threadIdx.x;
    if (tid >= B_SZ * H_N * D_N) return;
    int d = tid & 63;
    int bh = tid >> 6;
    size_t base = (size_t)bh * NCH * D_N + d;
    const size_t NT = (size_t)B_SZ * H_N * NCH * D_N;
    float r0 = 0.f, r1 = 0.f, r2 = 0.f, r3 = 0.f;
    for (int c = 0; c < NCH; ++c) {
        size_t i = base + (size_t)c * D_N;
        float a = cs[i], b2 = cs[NT + i], c2 = cs[2 * NT + i], d2 = cs[3 * NT + i];
        cs[i] = r0; cs[NT + i] = r1; cs[2 * NT + i] = r2; cs[3 * NT + i] = r3;
        r0 += a; r1 += b2; r2 += c2; r3 += d2;
    }
}

__global__ __launch_bounds__(256) void scan_pass3(
    const u16* __restrict__ vArr, const u16* __restrict__ phase,
    const float* __restrict__ cs, const float* __restrict__ gate,
    u16* __restrict__ y)
{
    int gw = (blockIdx.x * 256 + threadIdx.x) >> 6;
    int d = threadIdx.x & 63;
    int c = gw & (NCH - 1);
    int h = (gw >> 7) & (H_N - 1);
    int b = gw >> 11;

    double fd = 6.283185307179586 * ((double)(h + 1) / 16.0)
              * pow(10000.0, -(double)d / 64.0);
    float g0 = gate[h * 2 + 0];
    float g1 = gate[h * 2 + 1];

    int t0 = c * CH;
    size_t base = ((size_t)b * T_LEN + t0) * HD + (size_t)h * D_N + d;

    const size_t NT = (size_t)B_SZ * H_N * NCH * D_N;
    size_t ci = (size_t)gw * D_N + d;
    float ap_re = cs[ci];
    float ap_im = cs[NT + ci];
    float aa_re = cs[2 * NT + ci];
    float aa_im = cs[3 * NT + ci];

    float cr, sr;
    rotor_sincos(t0, fd, &sr, &cr);
    float cf, sf;
    sincosf((float)fd, &sf, &cf);

    float cp = 0.f, spv = 0.f;
    if (t0 > 0) {
        float thp = h2f(phase[base - HD]);
        __sincosf(thp, &spv, &cp);
    }

    for (int i = 0; i < CH; ++i) {
        int t = t0 + i;
        size_t idx = base + (size_t)i * HD;
        float v = h2f(vArr[idx]);
        float th = h2f(phase[idx]);
        ap_re = fmaf(v, cr, ap_re);
        ap_im = fmaf(v, sr, ap_im);
        aa_re = fmaf(v, cp, aa_re);
        aa_im = fmaf(-v, spv, aa_im);
        float op = fmaf(ap_re, cr, ap_im * sr);
        float ck, sk;
        __sincosf(th, &sk, &ck);
        float oa = fmaf(aa_re, ck, -aa_im * sk);
        float sc = rsqrtf((float)(t + 1));
        y[idx] = f2h((g0 * op + g1 * oa) * sc);
        cp = ck; spv = sk;
        float nc = fmaf(cr, cf, -sr * sf);
        float ns = fmaf(sr, cf,  cr * sf);
        cr = nc; sr = ns;
    }
}

// ---------------- launch ----------------
extern "C" void kernel_launch(void* const* d_in, const int* in_sizes, int n_in,
                              void* d_out, int out_size, void* d_ws, size_t ws_size,
                              hipStream_t stream)
{
    const float* x    = (const float*)d_in[0];
    const float* Wk   = (const float*)d_in[1];
    const float* Wv   = (const float*)d_in[2];
    const float* Wo   = (const float*)d_in[3];
    const float* gate = (const float*)d_in[4];
    float* out = (float*)d_out;

    // ws layout (MiB offsets):
    //   0  : xh   [16384][1024] fp16 = 32   -- yb aliases it after merged GEMM
    //   32 : vb   [16384][1024] fp16 = 32
    //   64 : cs   4 * 2*16*128*64 f32 = 4
    //   68 : Wkv  [2048][1024] fp16  = 4    (10Wk | Wv)
    //   72 : Wob  [1024][1024] fp16  = 2
    //   74 : ph16 [16384][1024] fp16 = 32   (mod-2pi phase)   total 106 MiB
    char* wsb = (char*)d_ws;
    u16*   xh   = (u16*)wsb;
    u16*   yb   = (u16*)wsb;                      // alias: xh dead after merged GEMM
    u16*   vb   = (u16*)(wsb + (32ull << 20));
    float* cs   = (float*)(wsb + (64ull << 20));
    u16*   Wkv  = (u16*)(wsb + (68ull << 20));
    u16*   Wob  = (u16*)(wsb + (72ull << 20));
    u16*   ph16 = (u16*)(wsb + (74ull << 20));

    // all conversions in one launch: 16384 x-blocks + 3072 weight-blocks
    hipLaunchKernelGGL(conv_all, dim3(19456), dim3(256), 0, stream,
                       x, Wk, Wv, Wo, xh, Wkv, Wob);

    const dim3 gblk(512);

    // [phase | v] = xh @ [10Wk | Wv]^T  (M=16384, N=2048, K=1024),
    // M-split into two 256-block launches (1 block/CU each).
    hipLaunchKernelGGL(gemm_mfma256, dim3(8, 32), gblk, 0, stream,
                       xh, 1024, Wkv, 1024, (void*)ph16, 1024, (void*)vb, 1024, 3,
                       0, 2);
    hipLaunchKernelGGL(gemm_mfma256, dim3(8, 32), gblk, 0, stream,
                       xh, 1024, Wkv, 1024, (void*)ph16, 1024, (void*)vb, 1024, 3,
                       8192, 2);

    const int waves = B_SZ * H_N * NCH;   // 4096
    hipLaunchKernelGGL(scan_pass1, dim3(waves / 4), dim3(256), 0, stream, vb, ph16, cs);
    hipLaunchKernelGGL(scan_pass2, dim3(8), dim3(256), 0, stream, cs);
    hipLaunchKernelGGL(scan_pass3, dim3(waves / 4), dim3(256), 0, stream, vb, ph16, cs, gate, yb);

    // out = yb @ Wo^T   (M=16384, N=1024, K=1024) -> d_out f32
    hipLaunchKernelGGL(gemm_mfma256, dim3(4, 64), gblk, 0, stream,
                       yb, 1024, Wob, 1024, (void*)out, HD, (void*)0, 1024, 0,
                       0, 3);
}